// Round 7
// baseline (458.531 us; speedup 1.0000x reference)
//
#include <hip/hip_runtime.h>
#include <hip/hip_bf16.h>

typedef unsigned short u16;
typedef __attribute__((ext_vector_type(8))) short bf16x8;
typedef __attribute__((ext_vector_type(4))) float f32x4;

#define N_TOK 4096
#define DMODEL 3072
#define NH 16
#define DHEAD 64
#define INNER 1024
#define SCALE_LOG2E 0.18033688011112042f  /* (1/8) * log2(e) */

__device__ __forceinline__ u16 f2bf(float f) {
    union { float f; unsigned u; } un; un.f = f;
    unsigned r = un.u + 0x7fffu + ((un.u >> 16) & 1u);
    return (u16)(r >> 16);
}
__device__ __forceinline__ float bf2f(u16 u) {
    union { unsigned u; float f; } x; x.u = ((unsigned)u) << 16; return x.f;
}
// pack two f32 -> two bf16 (round-half-up) in 3 VALU ops; a -> low 16
__device__ __forceinline__ unsigned pk2bf(float a, float b) {
    union { float f; unsigned u; } ua, ub; ua.f = a; ub.f = b;
    return __builtin_amdgcn_perm(ub.u + 0x8000u, ua.u + 0x8000u, 0x07060302u);
}
// merge low16 halves:  (a & 0xffff) | (b << 16)
__device__ __forceinline__ unsigned mlo(unsigned a, unsigned b) {
    return __builtin_amdgcn_perm(b, a, 0x05040100u);
}
// merge high16 halves: (a >> 16) | (b & 0xffff0000)
__device__ __forceinline__ unsigned mhi(unsigned a, unsigned b) {
    return __builtin_amdgcn_perm(b, a, 0x07060302u);
}
__device__ __forceinline__ void load_lds16(const u16* g, u16* l) {
    __builtin_amdgcn_global_load_lds(
        (const __attribute__((address_space(1))) unsigned int*)g,
        (__attribute__((address_space(3))) unsigned int*)l, 16, 0, 0);
}

// ---------------- prep: LN (blocks 0..4095) + w_qkv cvt + w_out cvt -------
#define WQ_BLOCKS 9216   /* 3*1024*3072/4/256 */
#define WO_BLOCKS 3072   /* 3072*1024/4/256 */
__global__ __launch_bounds__(256) void prep(const float* __restrict__ x,
                                            const float* __restrict__ g,
                                            const float* __restrict__ b,
                                            u16* __restrict__ xn,
                                            const float* __restrict__ w_qkv,
                                            u16* __restrict__ wq,
                                            const float* __restrict__ w_out,
                                            u16* __restrict__ wo) {
    int blk = blockIdx.x;
    int tid = threadIdx.x;
    if (blk >= N_TOK) {
        const float* src; u16* dst; int i;
        if (blk < N_TOK + WQ_BLOCKS) { src = w_qkv; dst = wq; i = (blk - N_TOK) * 256 + tid; }
        else { src = w_out; dst = wo; i = (blk - N_TOK - WQ_BLOCKS) * 256 + tid; }
        float4 v = ((const float4*)src)[i];
        ushort4 o;
        o.x = f2bf(v.x); o.y = f2bf(v.y); o.z = f2bf(v.z); o.w = f2bf(v.w);
        ((ushort4*)dst)[i] = o;
        return;
    }
    int row = blk;
    const float4* xr = (const float4*)(x + (size_t)row * DMODEL);
    float4 v[3];
    float s = 0.f, ss = 0.f;
#pragma unroll
    for (int i = 0; i < 3; ++i) {
        v[i] = xr[i * 256 + tid];
        s  += v[i].x + v[i].y + v[i].z + v[i].w;
        ss += v[i].x * v[i].x + v[i].y * v[i].y + v[i].z * v[i].z + v[i].w * v[i].w;
    }
#pragma unroll
    for (int off = 32; off; off >>= 1) {
        s  += __shfl_xor(s, off);
        ss += __shfl_xor(ss, off);
    }
    __shared__ float red[8];
    int wid = tid >> 6, lane = tid & 63;
    if (lane == 0) { red[wid] = s; red[wid + 4] = ss; }
    __syncthreads();
    s  = red[0] + red[1] + red[2] + red[3];
    ss = red[4] + red[5] + red[6] + red[7];
    float mean = s * (1.f / DMODEL);
    float var  = ss * (1.f / DMODEL) - mean * mean;
    float rstd = rsqrtf(var + 1e-5f);
    ushort4* orow = (ushort4*)(xn + (size_t)row * DMODEL);
#pragma unroll
    for (int i = 0; i < 3; ++i) {
        float4 gg = ((const float4*)g)[i * 256 + tid];
        float4 bb = ((const float4*)b)[i * 256 + tid];
        ushort4 o;
        o.x = f2bf((v[i].x - mean) * rstd * gg.x + bb.x);
        o.y = f2bf((v[i].y - mean) * rstd * gg.y + bb.y);
        o.z = f2bf((v[i].z - mean) * rstd * gg.z + bb.z);
        o.w = f2bf((v[i].w - mean) * rstd * gg.w + bb.w);
        orow[i * 256 + tid] = o;
    }
}

// ------- QKV GEMM with fused epilogue: writes Qr (rope+scale), Kr (rope),
// ------- Vt (transpose) directly. A = xn[4096,3072], B = wq[3072,3072].
// bx 0..7 -> Q cols, 8..15 -> K, 16..23 -> V.
__global__ __launch_bounds__(256) void gemm_qkv(const u16* __restrict__ A,
                                                const u16* __restrict__ B,
                                                const float* __restrict__ pe,
                                                u16* __restrict__ Qr,
                                                u16* __restrict__ Kr,
                                                u16* __restrict__ Vt) {
    __shared__ u16 sbuf[8704];               // 17408 B: As/Bs (16384) | epi tile 64x136
    u16* As = sbuf;
    u16* Bs = sbuf + 4096;
    int tid = threadIdx.x;
    int lane = tid & 63, wid = tid >> 6;
    int wm = wid >> 1, wn = wid & 1;
    int l15 = lane & 15, quad = lane >> 4;
    int m0 = blockIdx.y * 128, n0 = blockIdx.x * 128;
    const int K = DMODEL;

    f32x4 zero4 = {0.f, 0.f, 0.f, 0.f};
    f32x4 acc[4][4];
#pragma unroll
    for (int i = 0; i < 4; ++i)
#pragma unroll
        for (int j = 0; j < 4; ++j) acc[i][j] = zero4;

    const u16* Ab = A + (size_t)m0 * K;
    const u16* Bb = B + (size_t)n0 * K;
    int row0 = tid >> 2, c0 = (((tid & 3) ^ ((lane >> 3) & 3)) * 8);
    int row1 = row0 + 64;
    int rsw = (l15 >> 1) & 3;

    for (int k0 = 0; k0 < K; k0 += 32) {
        load_lds16(Ab + (size_t)row0 * K + k0 + c0, &As[wid * 512]);
        load_lds16(Ab + (size_t)row1 * K + k0 + c0, &As[2048 + wid * 512]);
        load_lds16(Bb + (size_t)row0 * K + k0 + c0, &Bs[wid * 512]);
        load_lds16(Bb + (size_t)row1 * K + k0 + c0, &Bs[2048 + wid * 512]);
        __syncthreads();
        bf16x8 a[4], b[4];
#pragma unroll
        for (int t = 0; t < 4; ++t) {
            a[t] = *(const bf16x8*)&As[(wm * 64 + t * 16 + l15) * 32 + ((quad ^ rsw) * 8)];
            b[t] = *(const bf16x8*)&Bs[(wn * 64 + t * 16 + l15) * 32 + ((quad ^ rsw) * 8)];
        }
#pragma unroll
        for (int mt = 0; mt < 4; ++mt)
#pragma unroll
            for (int nt = 0; nt < 4; ++nt)
                acc[mt][nt] = __builtin_amdgcn_mfma_f32_16x16x32_bf16(a[mt], b[nt], acc[mt][nt], 0, 0, 0);
        __syncthreads();
    }

    // ---- fused epilogue: two 64-row passes through LDS tile [64][136] ----
    u16* tile = sbuf;                         // stride 136 u16 (272 B, 16B-aligned)
    int region = n0 >> 10;                    // 0=Q, 1=K, 2=V
    int n0l = n0 & 1023;

#pragma unroll
    for (int p = 0; p < 2; ++p) {
        if (p) __syncthreads();
        if (wm == p) {
#pragma unroll
            for (int mt = 0; mt < 4; ++mt)
#pragma unroll
                for (int nt = 0; nt < 4; ++nt)
#pragma unroll
                    for (int r = 0; r < 4; ++r)
                        tile[(mt * 16 + quad * 4 + r) * 136 + wn * 64 + nt * 16 + l15] =
                            f2bf(acc[mt][nt][r]);
        }
        __syncthreads();

        if (region < 2) {
            // ---- Q/K: rope pairs ----
            int rl = tid >> 2;                // 0..63
            int ch = (tid & 3) * 32;          // col chunk
            int n  = m0 + p * 64 + rl;
            int cg = n0l + ch;
            int h  = cg >> 6;
            int dbase = cg & 63;
            float sc = (region == 0) ? SCALE_LOG2E : 1.0f;
            u16* outb = (region == 0) ? Qr : Kr;
            const float4* pev = (const float4*)pe + (size_t)n * 32 + (dbase >> 1);
            u16* orow = outb + ((size_t)h * N_TOK + n) * DHEAD + dbase;
#pragma unroll
            for (int k = 0; k < 4; ++k) {     // 4 pairs per chunk
                uint4 td = *(const uint4*)&tile[rl * 136 + ch + k * 8];
                float4 w0 = pev[k * 4 + 0];
                float4 w1 = pev[k * 4 + 1];
                float4 w2 = pev[k * 4 + 2];
                float4 w3 = pev[k * 4 + 3];
                float a0 = bf2f((u16)td.x), b0 = bf2f((u16)(td.x >> 16));
                float a1 = bf2f((u16)td.y), b1 = bf2f((u16)(td.y >> 16));
                float a2 = bf2f((u16)td.z), b2 = bf2f((u16)(td.z >> 16));
                float a3 = bf2f((u16)td.w), b3 = bf2f((u16)(td.w >> 16));
                uint4 ov;
                ov.x = pk2bf((w0.x * a0 + w0.y * b0) * sc, (w0.z * a0 + w0.w * b0) * sc);
                ov.y = pk2bf((w1.x * a1 + w1.y * b1) * sc, (w1.z * a1 + w1.w * b1) * sc);
                ov.z = pk2bf((w2.x * a2 + w2.y * b2) * sc, (w2.z * a2 + w2.w * b2) * sc);
                ov.w = pk2bf((w3.x * a3 + w3.y * b3) * sc, (w3.z * a3 + w3.w * b3) * sc);
                *(uint4*)&orow[k * 8] = ov;
            }
        } else {
            // ---- V: transpose to Vt[h][d][n] ----
            int c  = (tid & 63) * 2;          // even col
            int rq = (wid) * 16;              // 16-row quarter per wave
            int cg = n0l + c;
            int h = cg >> 6, d = cg & 63;
            int nb = m0 + p * 64 + rq;
            u16* vrow0 = Vt + ((size_t)(h * 64 + d)) * N_TOK + nb;
            u16* vrow1 = vrow0 + N_TOK;
            unsigned lo[8], hi[8];
#pragma unroll
            for (int k = 0; k < 4; ++k) {
                unsigned v0 = *(const unsigned*)&tile[(rq + 4 * k + 0) * 136 + c];
                unsigned v1 = *(const unsigned*)&tile[(rq + 4 * k + 1) * 136 + c];
                unsigned v2 = *(const unsigned*)&tile[(rq + 4 * k + 2) * 136 + c];
                unsigned v3 = *(const unsigned*)&tile[(rq + 4 * k + 3) * 136 + c];
                lo[2 * k] = mlo(v0, v1); lo[2 * k + 1] = mlo(v2, v3);
                hi[2 * k] = mhi(v0, v1); hi[2 * k + 1] = mhi(v2, v3);
            }
            ((uint4*)vrow0)[0] = *(uint4*)&lo[0];
            ((uint4*)vrow0)[1] = *(uint4*)&lo[4];
            ((uint4*)vrow1)[0] = *(uint4*)&hi[0];
            ((uint4*)vrow1)[1] = *(uint4*)&hi[4];
        }
    }
}

// ---------------- GEMM C = A * B^T ; f32 C (out projection) ----------------
template <int CBF16>
__global__ __launch_bounds__(256) void gemm_bt(const u16* __restrict__ A,
                                               const u16* __restrict__ B,
                                               void* __restrict__ C,
                                               int M, int Nn, int K) {
    __shared__ u16 As[128 * 32];
    __shared__ u16 Bs[128 * 32];
    int tid = threadIdx.x;
    int lane = tid & 63, wid = tid >> 6;
    int wm = wid >> 1, wn = wid & 1;
    int l15 = lane & 15, quad = lane >> 4;
    int m0 = blockIdx.y * 128, n0 = blockIdx.x * 128;

    f32x4 zero4 = {0.f, 0.f, 0.f, 0.f};
    f32x4 acc[4][4];
#pragma unroll
    for (int i = 0; i < 4; ++i)
#pragma unroll
        for (int j = 0; j < 4; ++j) acc[i][j] = zero4;

    const u16* Ab = A + (size_t)m0 * K;
    const u16* Bb = B + (size_t)n0 * K;
    int row0 = tid >> 2, c0 = (((tid & 3) ^ ((lane >> 3) & 3)) * 8);
    int row1 = row0 + 64;
    int rsw = (l15 >> 1) & 3;

    for (int k0 = 0; k0 < K; k0 += 32) {
        load_lds16(Ab + (size_t)row0 * K + k0 + c0, &As[wid * 512]);
        load_lds16(Ab + (size_t)row1 * K + k0 + c0, &As[2048 + wid * 512]);
        load_lds16(Bb + (size_t)row0 * K + k0 + c0, &Bs[wid * 512]);
        load_lds16(Bb + (size_t)row1 * K + k0 + c0, &Bs[2048 + wid * 512]);
        __syncthreads();
        bf16x8 a[4], b[4];
#pragma unroll
        for (int t = 0; t < 4; ++t) {
            a[t] = *(const bf16x8*)&As[(wm * 64 + t * 16 + l15) * 32 + ((quad ^ rsw) * 8)];
            b[t] = *(const bf16x8*)&Bs[(wn * 64 + t * 16 + l15) * 32 + ((quad ^ rsw) * 8)];
        }
#pragma unroll
        for (int mt = 0; mt < 4; ++mt)
#pragma unroll
            for (int nt = 0; nt < 4; ++nt)
                acc[mt][nt] = __builtin_amdgcn_mfma_f32_16x16x32_bf16(a[mt], b[nt], acc[mt][nt], 0, 0, 0);
        __syncthreads();
    }
#pragma unroll
    for (int mt = 0; mt < 4; ++mt)
#pragma unroll
        for (int nt = 0; nt < 4; ++nt)
#pragma unroll
            for (int r = 0; r < 4; ++r) {
                int rr = m0 + wm * 64 + mt * 16 + quad * 4 + r;
                int cc = n0 + wn * 64 + nt * 16 + l15;
                if (CBF16)
                    ((u16*)C)[(size_t)rr * Nn + cc] = f2bf(acc[mt][nt][r]);
                else
                    ((float*)C)[(size_t)rr * Nn + cc] = acc[mt][nt][r];
            }
}

// ---------------- Flash attention (fixed-bias softmax, no online max) -----
__global__ __launch_bounds__(256, 2) void flash_attn(const u16* __restrict__ Q,
                                                     const u16* __restrict__ K,
                                                     const u16* __restrict__ Vt,
                                                     u16* __restrict__ O) {
    __shared__ u16 lds_all[16384];           // 32 KB
    u16* Ks = lds_all;
    u16* Vs = lds_all + 4096;
    int tid = threadIdx.x, lane = tid & 63, wid = tid >> 6;
    u16* Ps = lds_all + 8192 + wid * 2048;
    int l15 = lane & 15, quad = lane >> 4;
    int sw = l15 & 7;
    int h = blockIdx.y;
    int q0 = blockIdx.x * 128 + wid * 32;
    const u16* Qh = Q + (size_t)h * N_TOK * DHEAD;
    const u16* Kh = K + (size_t)h * N_TOK * DHEAD;
    const u16* Vh = Vt + (size_t)h * DHEAD * N_TOK;

    f32x4 zero4 = {0.f, 0.f, 0.f, 0.f};
    bf16x8 ones;
#pragma unroll
    for (int i = 0; i < 8; ++i) ones[i] = (short)0x3F80;  // bf16 1.0

    bf16x8 aq[2][2];
#pragma unroll
    for (int mtQ = 0; mtQ < 2; ++mtQ)
#pragma unroll
        for (int kc = 0; kc < 2; ++kc)
            aq[mtQ][kc] = *(const bf16x8*)&Qh[(size_t)(q0 + mtQ * 16 + l15) * DHEAD + kc * 32 + quad * 8];

    f32x4 o[2][4], lacc[2];
#pragma unroll
    for (int mtQ = 0; mtQ < 2; ++mtQ) {
#pragma unroll
        for (int dt = 0; dt < 4; ++dt) o[mtQ][dt] = zero4;
        lacc[mtQ] = zero4;
    }

    int rbase = wid * 16;
    int rowoff = lane >> 3;
    int csw = ((lane & 7) ^ rowoff) * 8;

    for (int kt = 0; kt < N_TOK; kt += 64) {
        load_lds16(&Kh[(size_t)(kt + rbase + rowoff) * DHEAD + csw], &Ks[rbase * 64]);
        load_lds16(&Kh[(size_t)(kt + rbase + 8 + rowoff) * DHEAD + csw], &Ks[(rbase + 8) * 64]);
        load_lds16(&Vh[(size_t)(rbase + rowoff) * N_TOK + kt + csw], &Vs[rbase * 64]);
        load_lds16(&Vh[(size_t)(rbase + 8 + rowoff) * N_TOK + kt + csw], &Vs[(rbase + 8) * 64]);
        __syncthreads();

        bf16x8 bk[4][2], av[4][2];
#pragma unroll
        for (int t = 0; t < 4; ++t)
#pragma unroll
            for (int kc = 0; kc < 2; ++kc) {
                int off = (t * 16 + l15) * 64 + (((kc * 4 + quad) ^ sw) * 8);
                bk[t][kc] = *(const bf16x8*)&Ks[off];
                av[t][kc] = *(const bf16x8*)&Vs[off];
            }
        __syncthreads();

#pragma unroll
        for (int mtQ = 0; mtQ < 2; ++mtQ) {
            f32x4 s[4];
#pragma unroll
            for (int ntK = 0; ntK < 4; ++ntK) {
                f32x4 t0 = __builtin_amdgcn_mfma_f32_16x16x32_bf16(bk[ntK][0], aq[mtQ][0], zero4, 0, 0, 0);
                s[ntK] = __builtin_amdgcn_mfma_f32_16x16x32_bf16(bk[ntK][1], aq[mtQ][1], t0, 0, 0, 0);
            }
#pragma unroll
            for (int ntK = 0; ntK < 4; ++ntK) {
                uint2 pv;
                pv.x = pk2bf(__builtin_amdgcn_exp2f(s[ntK][0]), __builtin_amdgcn_exp2f(s[ntK][1]));
                pv.y = pk2bf(__builtin_amdgcn_exp2f(s[ntK][2]), __builtin_amdgcn_exp2f(s[ntK][3]));
                int pc = (ntK * 2 + (quad >> 1)) ^ sw;
                *(uint2*)&Ps[(mtQ * 16 + l15) * 64 + pc * 8 + (quad & 1) * 4] = pv;
            }
            bf16x8 bp0 = *(const bf16x8*)&Ps[(mtQ * 16 + l15) * 64 + ((quad ^ sw) * 8)];
            bf16x8 bp1 = *(const bf16x8*)&Ps[(mtQ * 16 + l15) * 64 + (((4 + quad) ^ sw) * 8)];
            lacc[mtQ] = __builtin_amdgcn_mfma_f32_16x16x32_bf16(ones, bp0, lacc[mtQ], 0, 0, 0);
            lacc[mtQ] = __builtin_amdgcn_mfma_f32_16x16x32_bf16(ones, bp1, lacc[mtQ], 0, 0, 0);
#pragma unroll
            for (int dt = 0; dt < 4; ++dt) {
                o[mtQ][dt] = __builtin_amdgcn_mfma_f32_16x16x32_bf16(av[dt][0], bp0, o[mtQ][dt], 0, 0, 0);
                o[mtQ][dt] = __builtin_amdgcn_mfma_f32_16x16x32_bf16(av[dt][1], bp1, o[mtQ][dt], 0, 0, 0);
            }
        }
    }

    __syncthreads();
    u16* scratch = lds_all + wid * 2048;
#pragma unroll
    for (int mtQ = 0; mtQ < 2; ++mtQ) {
        float rl = 1.f / lacc[mtQ][0];
#pragma unroll
        for (int dt = 0; dt < 4; ++dt) {
            uint2 ov;
            ov.x = pk2bf(o[mtQ][dt][0] * rl, o[mtQ][dt][1] * rl);
            ov.y = pk2bf(o[mtQ][dt][2] * rl, o[mtQ][dt][3] * rl);
            *(uint2*)&scratch[(mtQ * 16 + l15) * 64 + dt * 16 + quad * 4] = ov;
        }
    }
#pragma unroll
    for (int p = 0; p < 4; ++p) {
        int q_local = p * 8 + (lane >> 3);
        int dcol = (lane & 7) * 8;
        bf16x8 v = *(const bf16x8*)&scratch[q_local * 64 + dcol];
        *(bf16x8*)&O[(size_t)(q0 + q_local) * INNER + h * 64 + dcol] = v;
    }
}

extern "C" void kernel_launch(void* const* d_in, const int* in_sizes, int n_in,
                              void* d_out, int out_size, void* d_ws, size_t ws_size,
                              hipStream_t stream) {
    const float* x     = (const float*)d_in[0];
    const float* pe    = (const float*)d_in[1];
    const float* w_qkv = (const float*)d_in[2];
    const float* w_out = (const float*)d_in[3];
    const float* ln_g  = (const float*)d_in[4];
    const float* ln_b  = (const float*)d_in[5];
    float* out = (float*)d_out;

    char* ws = (char*)d_ws;
    u16* xn  = (u16*)ws;  ws += (size_t)N_TOK * DMODEL * 2;
    u16* wq  = (u16*)ws;  ws += (size_t)3 * INNER * DMODEL * 2;
    u16* wo  = (u16*)ws;  ws += (size_t)DMODEL * INNER * 2;
    u16* Qr  = (u16*)ws;  ws += (size_t)NH * N_TOK * DHEAD * 2;
    u16* Kr  = (u16*)ws;  ws += (size_t)NH * N_TOK * DHEAD * 2;
    u16* Vt  = (u16*)ws;  ws += (size_t)NH * DHEAD * N_TOK * 2;
    u16* Ob  = (u16*)ws;  ws += (size_t)N_TOK * INNER * 2;

    prep<<<N_TOK + WQ_BLOCKS + WO_BLOCKS, 256, 0, stream>>>(x, ln_g, ln_b, xn, w_qkv, wq, w_out, wo);
    gemm_qkv<<<dim3(DMODEL / 128, N_TOK / 128), 256, 0, stream>>>(xn, wq, pe, Qr, Kr, Vt);
    flash_attn<<<dim3(N_TOK / 128, NH), 256, 0, stream>>>(Qr, Kr, Vt, Ob);
    gemm_bt<0><<<dim3(DMODEL / 128, N_TOK / 128), 256, 0, stream>>>(Ob, wo, out, N_TOK, DMODEL, INNER);
}